// Round 1
// baseline (13908.698 us; speedup 1.0000x reference)
//
#include <hip/hip_runtime.h>
#include <hip/hip_bf16.h>

#define S_LEN 4096
#define DIM   256
#define HID   512
#define G4    2048
#define NE    2000
#define NL    20
#define KWG   16   // workgroups per direction in persistent LSTM

__device__ __forceinline__ float sigmoidf_(float x) { return 1.f / (1.f + expf(-x)); }

// ---------------------------------------------------------------------------
// Kernel 1: input projection  xw[dir][t][j] = sum_k emb[sentence[t]][k]*Wi[j][k] + b[j]
// grid: (256 t-blocks of 16 rows, 2 j-blocks of 1024, 2 dirs), block 256
// ---------------------------------------------------------------------------
__global__ __launch_bounds__(256) void xw_gemm(const int* __restrict__ sentence,
                                               const float* __restrict__ emb,
                                               const float* __restrict__ Wi_f,
                                               const float* __restrict__ b_f,
                                               const float* __restrict__ Wi_b,
                                               const float* __restrict__ b_b,
                                               float* __restrict__ xwf,
                                               float* __restrict__ xwb)
{
    const int tblk = blockIdx.x, jblk = blockIdx.y, dir = blockIdx.z;
    const float* Wi = dir ? Wi_b : Wi_f;
    const float* bb = dir ? b_b : b_f;
    float* xw = dir ? xwb : xwf;

    __shared__ float4 xs[16][64];   // 16 rows of x, 256 floats each (16 KB)
    const int tid = threadIdx.x;
    {
        const int r = tid >> 4, q0 = tid & 15;
        const int srow = sentence[tblk * 16 + r];
        const float4* er = (const float4*)(emb + (size_t)srow * DIM);
#pragma unroll
        for (int q = 0; q < 4; ++q) xs[r][q0 * 4 + q] = er[q0 * 4 + q];
    }
    __syncthreads();

    float acc[16][4];
#pragma unroll
    for (int t = 0; t < 16; ++t)
#pragma unroll
        for (int q = 0; q < 4; ++q) acc[t][q] = 0.f;

    const float4* Wi4 = (const float4*)Wi;
    const int j0 = jblk * 1024 + tid;
    for (int kk = 0; kk < 64; ++kk) {
        float4 wv0 = Wi4[(j0)*64 + kk];
        float4 wv1 = Wi4[(j0 + 256) * 64 + kk];
        float4 wv2 = Wi4[(j0 + 512) * 64 + kk];
        float4 wv3 = Wi4[(j0 + 768) * 64 + kk];
#pragma unroll
        for (int t = 0; t < 16; ++t) {
            float4 xv = xs[t][kk];
            acc[t][0] = fmaf(xv.x, wv0.x, fmaf(xv.y, wv0.y, fmaf(xv.z, wv0.z, fmaf(xv.w, wv0.w, acc[t][0]))));
            acc[t][1] = fmaf(xv.x, wv1.x, fmaf(xv.y, wv1.y, fmaf(xv.z, wv1.z, fmaf(xv.w, wv1.w, acc[t][1]))));
            acc[t][2] = fmaf(xv.x, wv2.x, fmaf(xv.y, wv2.y, fmaf(xv.z, wv2.z, fmaf(xv.w, wv2.w, acc[t][2]))));
            acc[t][3] = fmaf(xv.x, wv3.x, fmaf(xv.y, wv3.y, fmaf(xv.z, wv3.z, fmaf(xv.w, wv3.w, acc[t][3]))));
        }
    }
#pragma unroll
    for (int q = 0; q < 4; ++q) {
        const int j = j0 + q * 256;
        const float bj = bb[j];
#pragma unroll
        for (int t = 0; t < 16; ++t)
            xw[(size_t)(tblk * 16 + t) * G4 + j] = acc[t][q] + bj;
    }
}

// ---------------------------------------------------------------------------
// Kernel 2: persistent BiLSTM. 32 WGs (16 per direction), 256 threads each.
// WG w of a direction owns h-slice [w*32, w*32+32) -> 128 rows of Wh
// (gate g rows g*512 + w*32 .. +32), kept entirely in VGPRs (256/thread).
// Per step: register matvec, 8-lane shfl reduce, wave0 does gates + publishes
// h slice to global, device-scope counter barrier, reload h[512] into LDS.
// ---------------------------------------------------------------------------
__global__ __launch_bounds__(256, 1) void lstm_kernel(const float* __restrict__ xwf,
                                                      const float* __restrict__ xwb,
                                                      const float* __restrict__ Wh_f,
                                                      const float* __restrict__ Wh_b,
                                                      float* __restrict__ hf,
                                                      float* __restrict__ hb,
                                                      unsigned* __restrict__ cnt)
{
    const int wg = blockIdx.x & (KWG - 1);
    const int dir = blockIdx.x >> 4;
    const float* xw = dir ? xwb : xwf;
    const float* Wh = dir ? Wh_b : Wh_f;
    float* hout = dir ? hb : hf;
    unsigned* cn = cnt + (size_t)dir * S_LEN;

    const int tid = threadIdx.x;
    const int wv = tid >> 6;          // wave 0..3  == gate index
    const int ln = tid & 63;
    const int cchunk = ln & 7;        // 8 column chunks of 64
    const int rl = ln >> 3;           // 8 row groups of 4 rows per wave

    // load weights: rows = wv*512 + wg*32 + rl*4 + m, cols = cchunk*64 + ...
    float wreg[4][64];
    {
        const float* wb = Wh + (size_t)(wv * HID + wg * 32 + rl * 4) * HID + cchunk * 64;
#pragma unroll
        for (int m = 0; m < 4; ++m) {
            const float4* w4 = (const float4*)(wb + m * HID);
#pragma unroll
            for (int kk = 0; kk < 16; ++kk) {
                float4 v = w4[kk];
                wreg[m][kk * 4 + 0] = v.x;
                wreg[m][kk * 4 + 1] = v.y;
                wreg[m][kk * 4 + 2] = v.z;
                wreg[m][kk * 4 + 3] = v.w;
            }
        }
    }

    __shared__ float hsh[8 * 68];   // h, chunk-padded (68 pitch -> bank-spread)
    __shared__ float zsh[128];      // [gate*32 + hloc] pre-activations
    for (int i = tid; i < 8 * 68; i += 256) hsh[i] = 0.f;
    float cst = 0.f;                // cell state (wave0 lanes 0..31)
    __syncthreads();

    for (int s = 0; s < S_LEN; ++s) {
        const int t = dir ? (S_LEN - 1 - s) : s;

        // prefetch this step's input-projection slice (independent of h)
        float xwv0 = 0.f, xwv1 = 0.f, xwv2 = 0.f, xwv3 = 0.f;
        if (tid < 32) {
            const float* xr = xw + (size_t)t * G4 + wg * 32 + tid;
            xwv0 = xr[0];
            xwv1 = xr[512];
            xwv2 = xr[1024];
            xwv3 = xr[1536];
        }

        // matvec partials: 4 rows x 64 cols per thread
        float s0 = 0.f, s1 = 0.f, s2 = 0.f, s3 = 0.f;
        {
            const float4* hb4 = (const float4*)(hsh + cchunk * 68);
#pragma unroll
            for (int kk = 0; kk < 16; ++kk) {
                float4 hv = hb4[kk];
                const float hvv[4] = {hv.x, hv.y, hv.z, hv.w};
#pragma unroll
                for (int q = 0; q < 4; ++q) {
                    s0 = fmaf(wreg[0][kk * 4 + q], hvv[q], s0);
                    s1 = fmaf(wreg[1][kk * 4 + q], hvv[q], s1);
                    s2 = fmaf(wreg[2][kk * 4 + q], hvv[q], s2);
                    s3 = fmaf(wreg[3][kk * 4 + q], hvv[q], s3);
                }
            }
        }
        // reduce over the 8 column-chunk lanes
#pragma unroll
        for (int off = 1; off < 8; off <<= 1) {
            s0 += __shfl_xor(s0, off);
            s1 += __shfl_xor(s1, off);
            s2 += __shfl_xor(s2, off);
            s3 += __shfl_xor(s3, off);
        }
        if ((ln & 7) == 0) {
            zsh[wv * 32 + rl * 4 + 0] = s0;
            zsh[wv * 32 + rl * 4 + 1] = s1;
            zsh[wv * 32 + rl * 4 + 2] = s2;
            zsh[wv * 32 + rl * 4 + 3] = s3;
        }
        __syncthreads();

        // finalize gates on wave0 lanes 0..31 (one h element each)
        if (tid < 32) {
            const float zi = zsh[tid] + xwv0;
            const float zf = zsh[32 + tid] + xwv1;
            const float zg = zsh[64 + tid] + xwv2;
            const float zo = zsh[96 + tid] + xwv3;
            const float ig = sigmoidf_(zi);
            const float fg = sigmoidf_(zf);
            const float og = sigmoidf_(zo);
            const float gg = tanhf(zg);
            cst = fg * cst + ig * gg;
            const float hv = og * tanhf(cst);
            hout[(size_t)t * HID + wg * 32 + tid] = hv;
        }
        __syncthreads();

        // publish (release) + barrier across the direction's 16 WGs
        if (tid == 0) {
            __hip_atomic_fetch_add(cn + s, 1u, __ATOMIC_RELEASE, __HIP_MEMORY_SCOPE_AGENT);
            while (__hip_atomic_load(cn + s, __ATOMIC_ACQUIRE, __HIP_MEMORY_SCOPE_AGENT) < KWG)
                __builtin_amdgcn_s_sleep(1);
        }
        __syncthreads();

        // reload full h into LDS (chunk-padded layout)
        for (int i = tid; i < HID; i += 256)
            hsh[(i >> 6) * 68 + (i & 63)] = hout[(size_t)t * HID + i];
        __syncthreads();
    }
}

// ---------------------------------------------------------------------------
// Kernel 3: scores[t] = blstm[t] . attn_w + attn_b
// ---------------------------------------------------------------------------
__global__ __launch_bounds__(256) void score_kernel(const float* __restrict__ hf,
                                                    const float* __restrict__ hb,
                                                    const float* __restrict__ aw,
                                                    const float* __restrict__ ab,
                                                    float* __restrict__ scores)
{
    const int t = blockIdx.x;
    const int tid = threadIdx.x;
    float p = hf[(size_t)t * HID + tid] * aw[tid]
            + hf[(size_t)t * HID + 256 + tid] * aw[256 + tid]
            + hb[(size_t)t * HID + tid] * aw[512 + tid]
            + hb[(size_t)t * HID + 256 + tid] * aw[768 + tid];
#pragma unroll
    for (int off = 1; off < 64; off <<= 1) p += __shfl_xor(p, off);
    __shared__ float rsum[4];
    if ((tid & 63) == 0) rsum[tid >> 6] = p;
    __syncthreads();
    if (tid == 0) scores[t] = rsum[0] + rsum[1] + rsum[2] + rsum[3] + ab[0];
}

// ---------------------------------------------------------------------------
// Kernel 4: per-entity masked softmax over span scores + weighted sum of blstm
// ---------------------------------------------------------------------------
__global__ __launch_bounds__(256) void entity_kernel(const int* __restrict__ eidx,
                                                     const float* __restrict__ scores,
                                                     const float* __restrict__ hf,
                                                     const float* __restrict__ hb,
                                                     float* __restrict__ out)
{
    const int e = blockIdx.x;
    const int tid = threadIdx.x;
    __shared__ float wsh[NL];
    __shared__ int ish[NL];
    if (tid < 32) {
        const int l = tid;
        const int ix = (l < NL) ? eidx[e * NL + l] : -1;
        const float sc = (ix >= 0) ? scores[ix] : -1e9f;
        float mx = sc;
#pragma unroll
        for (int off = 1; off < 32; off <<= 1) mx = fmaxf(mx, __shfl_xor(mx, off));
        const float ex = (ix >= 0) ? expf(sc - mx) : 0.f;
        float sm = ex;
#pragma unroll
        for (int off = 1; off < 32; off <<= 1) sm += __shfl_xor(sm, off);
        if (l < NL) {
            wsh[l] = ex / sm;
            ish[l] = (ix >= 0) ? ix : 0;
        }
    }
    __syncthreads();
    for (int d0 = tid; d0 < 1024; d0 += 256) {
        const float* hsrc = (d0 < HID) ? hf : hb;
        const int dd = d0 & (HID - 1);
        float a = 0.f;
#pragma unroll
        for (int l = 0; l < NL; ++l) a += wsh[l] * hsrc[(size_t)ish[l] * HID + dd];
        out[(size_t)e * 1024 + d0] = a;
    }
}

// ---------------------------------------------------------------------------
extern "C" void kernel_launch(void* const* d_in, const int* in_sizes, int n_in,
                              void* d_out, int out_size, void* d_ws, size_t ws_size,
                              hipStream_t stream)
{
    const int*   sentence = (const int*)d_in[0];
    const int*   eidx     = (const int*)d_in[1];
    const float* emb      = (const float*)d_in[2];
    const float* Wi_f     = (const float*)d_in[3];
    const float* Wh_f     = (const float*)d_in[4];
    const float* b_f      = (const float*)d_in[5];
    const float* Wi_b     = (const float*)d_in[6];
    const float* Wh_b     = (const float*)d_in[7];
    const float* b_b      = (const float*)d_in[8];
    const float* attn_w   = (const float*)d_in[9];
    const float* attn_b   = (const float*)d_in[10];
    float* out = (float*)d_out;
    float* ws  = (float*)d_ws;

    // workspace layout (floats): xwf | xwb | hf | hb | scores | cnt
    const size_t XW = (size_t)S_LEN * G4;   // 8388608 floats per direction
    const size_t HS = (size_t)S_LEN * HID;  // 2097152 floats per direction
    float* xwf = ws;
    float* xwb = ws + XW;
    float* hf  = ws + 2 * XW;
    float* hb  = ws + 2 * XW + HS;
    float* sc  = ws + 2 * XW + 2 * HS;
    unsigned* cnt = (unsigned*)(ws + 2 * XW + 2 * HS + S_LEN);
    // total ~84 MB of d_ws used

    hipMemsetAsync(cnt, 0, 2 * S_LEN * sizeof(unsigned), stream);
    xw_gemm<<<dim3(256, 2, 2), dim3(256), 0, stream>>>(sentence, emb, Wi_f, b_f, Wi_b, b_b, xwf, xwb);
    lstm_kernel<<<dim3(2 * KWG), dim3(256), 0, stream>>>(xwf, xwb, Wh_f, Wh_b, hf, hb, cnt);
    score_kernel<<<dim3(S_LEN), dim3(256), 0, stream>>>(hf, hb, attn_w, attn_b, sc);
    entity_kernel<<<dim3(NE), dim3(256), 0, stream>>>(eidx, sc, hf, hb, out);
}